// Round 9
// baseline (454.076 us; speedup 1.0000x reference)
//
#include <hip/hip_runtime.h>
#include <math.h>

#define T_TOK 8192
#define DDIM 1024
#define HDIM 2048
#define NE 8

typedef float f32x4 __attribute__((ext_vector_type(4)));
typedef short short8 __attribute__((ext_vector_type(8)));
typedef __attribute__((address_space(3))) char as3_char;
typedef __attribute__((address_space(1))) const char as1_cchar;

__device__ __forceinline__ unsigned f2bf(float f) {
  unsigned u = __float_as_uint(f);
  return (u + 0x7fffu + ((u >> 16) & 1u)) >> 16;
}
__device__ __forceinline__ float gelu_exact(float v) {
  return 0.5f * v * (1.0f + erff(v * 0.70710678118654752f));
}

// ---------------- cast x -> bf16 ----------------
__global__ void cast_x_kernel(const float4* __restrict__ x4, uint4* __restrict__ xb4) {
  int i = blockIdx.x * blockDim.x + threadIdx.x;
  float4 a = x4[2 * i], b = x4[2 * i + 1];
  uint4 o;
  o.x = f2bf(a.x) | (f2bf(a.y) << 16);
  o.y = f2bf(a.z) | (f2bf(a.w) << 16);
  o.z = f2bf(b.x) | (f2bf(b.y) << 16);
  o.w = f2bf(b.z) | (f2bf(b.w) << 16);
  xb4[i] = o;
}

// ---------------- transpose + cast: in [E][R][C] f32 -> out [E][C][R] bf16, 64x64 tiles ----
__global__ __launch_bounds__(256) void transpose_cast64(const float* __restrict__ in,
                                                        unsigned short* __restrict__ out,
                                                        int R, int C) {
  __shared__ float tile[64][65];
  size_t eoff = (size_t)blockIdx.z * R * C;
  const int r0 = blockIdx.y << 6, c0 = blockIdx.x << 6;
  const int tid = threadIdx.x;
  const int lr = tid >> 4;          // 0..15
  const int lc4 = (tid & 15) << 2;  // 0,4,..,60
#pragma unroll
  for (int rr = 0; rr < 4; ++rr) {
    int r = lr + rr * 16;
    float4 v = *(const float4*)(in + eoff + (size_t)(r0 + r) * C + c0 + lc4);
    tile[r][lc4] = v.x; tile[r][lc4 + 1] = v.y; tile[r][lc4 + 2] = v.z; tile[r][lc4 + 3] = v.w;
  }
  __syncthreads();
  const int c = tid >> 2;           // 0..63
  const int rch = (tid & 3) << 4;   // 0,16,32,48
  unsigned short tmp[16];
#pragma unroll
  for (int i = 0; i < 16; ++i) tmp[i] = (unsigned short)f2bf(tile[rch + i][c]);
  unsigned short* dst = out + eoff + (size_t)(c0 + c) * R + r0 + rch;
  *(uint4*)dst = *(const uint4*)tmp;
  *(uint4*)(dst + 8) = *(const uint4*)(tmp + 8);
}

// ---------------- transpose router weights: Wg/Wn [D][E] f32 -> [E][D] f32 ----------------
__global__ void transpose_router_w(const float* __restrict__ Wg, const float* __restrict__ Wn,
                                   float* __restrict__ WgT, float* __restrict__ WnT) {
  int i = blockIdx.x * 256 + threadIdx.x;  // over D*E = 8192
  int d = i >> 3, e = i & 7;
  WgT[e * DDIM + d] = Wg[i];
  WnT[e * DDIM + d] = Wn[i];
}

// ---------------- router: 4 tokens/block, 8-lane group per expert, fp64 dots ----------------
__global__ __launch_bounds__(256) void router_kernel(
    const float* __restrict__ x, const float* __restrict__ noise,
    const float* __restrict__ WgT, const float* __restrict__ bg,
    const float* __restrict__ WnT, const float* __restrict__ bn,
    int* __restrict__ e0e1, float2* __restrict__ gg) {
  const int wid = threadIdx.x >> 6, l = threadIdx.x & 63;
  const int t = blockIdx.x * 4 + wid;
  const int g = l >> 3, j = l & 7;
  const float4* xp = (const float4*)(x + (size_t)t * DDIM) + j * 32;
  const float4* wg = (const float4*)(WgT + (size_t)g * DDIM) + j * 32;
  const float4* wn = (const float4*)(WnT + (size_t)g * DDIM) + j * 32;
  double sg = 0.0, sn = 0.0;
#pragma unroll
  for (int i = 0; i < 32; ++i) {
    float4 xv = xp[i], a = wg[i], b = wn[i];
    sg += (double)xv.x * a.x + (double)xv.y * a.y + (double)xv.z * a.z + (double)xv.w * a.w;
    sn += (double)xv.x * b.x + (double)xv.y * b.y + (double)xv.z * b.z + (double)xv.w * b.w;
  }
#pragma unroll
  for (int off = 1; off < 8; off <<= 1) {
    sg += __shfl_xor(sg, off);
    sn += __shfl_xor(sn, off);
  }
  double nl = sn + (double)bn[g];
  double sp = (nl > 30.0) ? nl : log1p(exp(nl));
  double nv = sg + (double)bg[g] + (double)noise[(size_t)t * 8 + g] * sp;
  double nva[8];
#pragma unroll
  for (int e = 0; e < 8; ++e) nva[e] = __shfl(nv, e << 3);
  int i0 = 0;
  double v0 = nva[0];
#pragma unroll
  for (int e = 1; e < 8; ++e)
    if (nva[e] > v0) { v0 = nva[e]; i0 = e; }
  int i1 = (i0 == 0) ? 1 : 0;
  double v1 = nva[i0 == 0 ? 1 : 0];
#pragma unroll
  for (int e = 0; e < 8; ++e)
    if (e != i0 && nva[e] > v1) { v1 = nva[e]; i1 = e; }
  if (l == 0) {
    double w1 = exp(v1 - v0);
    double s = 1.0 + w1;
    e0e1[t] = i0 | (i1 << 8);
    gg[t] = make_float2((float)(1.0 / s), (float)(w1 / s));
  }
}

// ---------------- deterministic compaction: 8 blocks (1/expert), 8 waves each ----------------
__global__ __launch_bounds__(512) void compact_kernel(
    const int* __restrict__ e0e1, const float2* __restrict__ gg,
    int* __restrict__ tok_list, float* __restrict__ gate_list,
    int* __restrict__ counts, int* __restrict__ bases) {
  __shared__ int cmat[8][8];  // [wave][expert]
  const int e = blockIdx.x;
  const int wid = threadIdx.x >> 6, l = threadIdx.x & 63;
  const int t0w = wid * (T_TOK / 8);
  int c[8] = {0, 0, 0, 0, 0, 0, 0, 0};
  for (int i = 0; i < T_TOK / 8 / 64; ++i) {
    int p = e0e1[t0w + i * 64 + l];
    int ea = p & 255, eb = (p >> 8) & 255;
#pragma unroll
    for (int ee = 0; ee < 8; ++ee)
      c[ee] += __popcll(__ballot(ea == ee || eb == ee));
  }
  if (l == 0) {
#pragma unroll
    for (int ee = 0; ee < 8; ++ee) cmat[wid][ee] = c[ee];
  }
  __syncthreads();
  int base = 0;
  for (int ee = 0; ee < 8; ++ee) {
    if (ee < e) {
#pragma unroll
      for (int w = 0; w < 8; ++w) base += cmat[w][ee];
    }
  }
  int off = base;
#pragma unroll
  for (int w = 0; w < 8; ++w)
    if (w < wid) off += cmat[w][e];
  if (threadIdx.x == 0) {
    int tot = 0;
#pragma unroll
    for (int w = 0; w < 8; ++w) tot += cmat[w][e];
    counts[e] = tot;
    bases[e] = base;
  }
  for (int i = 0; i < T_TOK / 8 / 64; ++i) {
    int t = t0w + i * 64 + l;
    int p = e0e1[t];
    int ea = p & 255, eb = (p >> 8) & 255;
    int k = (ea == e) ? 0 : ((eb == e) ? 1 : -1);
    unsigned long long m = __ballot(k >= 0);
    if (k >= 0) {
      int pos = __popcll(m & ((1ull << l) - 1ull));
      float2 g = gg[t];
      tok_list[off + pos] = t;
      gate_list[off + pos] = (k == 0) ? g.x : g.y;
    }
    off += __popcll(m);
  }
}

// =====================================================================================
// 256x256 BK=64 8-wave (2Mx4N, 128x64/wave) 2-phase GEMM — catalog T3 "minimum 2-phase":
//   STAGE(buf^1, t+1); ds_read buf; 128 MFMA; vmcnt(0)+barrier; buf^=1.
// LDS 128KB: per buf {A 256x64 bf16 (32KB) | B 256x64 (32KB)}; chunk^=(row&7) swizzle
// on BOTH gload-source and ds_read (involution, rule #21).
// =====================================================================================
template <bool IS_UP>
__global__ __launch_bounds__(512, 2) void moe_gemm256_2ph(
    const unsigned short* __restrict__ Abase, const unsigned short* __restrict__ Bbase,
    const float* __restrict__ bias, const int* __restrict__ tok_list,
    const float* __restrict__ gate_list, const int* __restrict__ counts,
    const int* __restrict__ bases, unsigned short* __restrict__ h_out,
    float* __restrict__ out) {
  constexpr int NT = IS_UP ? 16 : 32;        // K-tiles of 64
  constexpr int KB = IS_UP ? 2048 : 4096;    // K bytes per row
  constexpr int NDIM_ = IS_UP ? HDIM : DDIM;
  const int e = blockIdx.z;
  const int count = counts[e];
  const int tileM = blockIdx.y;
  if (tileM * 256 >= count) return;
  const int base = bases[e];
  const int tileN = blockIdx.x;

  __shared__ __align__(16) char lds[131072];

  const int tid = threadIdx.x;
  const int wid = tid >> 6, l = tid & 63;
  const int wr = wid >> 2, wc = wid & 3;     // 2M x 4N wave grid
  const int srow = tid >> 3, j8 = tid & 7;   // staging: 64 rows/piece, 8 lanes/row
  const int kc = (j8 ^ (srow & 7)) << 4;     // pre-swizzled global 16B chunk
  const int cm1 = count - 1;

  const char* gA[4];
  const char* gB[4];
#pragma unroll
  for (int i = 0; i < 4; ++i) {
    int r = i * 64 + srow;  // 0..255
    if (IS_UP) {
      int tok = tok_list[base + min(tileM * 256 + r, cm1)];
      gA[i] = (const char*)Abase + (size_t)tok * KB + kc;
    } else {
      gA[i] = (const char*)Abase + (size_t)(base + min(tileM * 256 + r, cm1)) * KB + kc;
    }
    gB[i] = (const char*)Bbase +
            ((size_t)e * NDIM_ * (IS_UP ? DDIM : HDIM) + (size_t)(tileN * 256 + r) * (IS_UP ? DDIM : HDIM)) * 2 + kc;
  }

  const int fr = l & 15, kg = l >> 4;
  int aoff[8][2], boff[4][2];
#pragma unroll
  for (int mi = 0; mi < 8; ++mi)
#pragma unroll
    for (int kk = 0; kk < 2; ++kk)
      aoff[mi][kk] = (wr * 128 + mi * 16 + fr) * 128 + ((((kk << 2) | kg) ^ (fr & 7)) << 4);
#pragma unroll
  for (int ni = 0; ni < 4; ++ni)
#pragma unroll
    for (int kk = 0; kk < 2; ++kk)
      boff[ni][kk] = 32768 + (wc * 64 + ni * 16 + fr) * 128 + ((((kk << 2) | kg) ^ (fr & 7)) << 4);

  f32x4 acc[8][4];
  const f32x4 zz = {0.f, 0.f, 0.f, 0.f};
#pragma unroll
  for (int mi = 0; mi < 8; ++mi)
#pragma unroll
    for (int ni = 0; ni < 4; ++ni) acc[mi][ni] = zz;

#define STG(bufb, kt) do {                                                              \
    _Pragma("unroll") for (int i = 0; i < 4; ++i)                                       \
      __builtin_amdgcn_global_load_lds((as1_cchar*)(gA[i] + (size_t)(kt) * 128),        \
          (as3_char*)lds + (bufb) + i * 8192 + tid * 16, 16, 0, 0);                     \
    _Pragma("unroll") for (int i = 0; i < 4; ++i)                                       \
      __builtin_amdgcn_global_load_lds((as1_cchar*)(gB[i] + (size_t)(kt) * 128),        \
          (as3_char*)lds + (bufb) + 32768 + i * 8192 + tid * 16, 16, 0, 0);             \
  } while (0)

  STG(0, 0);
  asm volatile("s_waitcnt vmcnt(0)" ::: "memory");
  __builtin_amdgcn_s_barrier();
  asm volatile("" ::: "memory");

  int bufoff = 0;
  for (int t = 0; t < NT; ++t) {
    if (t + 1 < NT) STG(bufoff ^ 65536, t + 1);  // issue next-tile loads FIRST
    const char* lb = lds + bufoff;
    short8 bfr[4][2];
#pragma unroll
    for (int ni = 0; ni < 4; ++ni) {
      bfr[ni][0] = *(const short8*)(lb + boff[ni][0]);
      bfr[ni][1] = *(const short8*)(lb + boff[ni][1]);
    }
    __builtin_amdgcn_s_setprio(1);
#pragma unroll
    for (int mi = 0; mi < 8; ++mi) {
      short8 a0 = *(const short8*)(lb + aoff[mi][0]);
      short8 a1 = *(const short8*)(lb + aoff[mi][1]);
#pragma unroll
      for (int ni = 0; ni < 4; ++ni) {
        acc[mi][ni] = __builtin_amdgcn_mfma_f32_16x16x32_bf16(a0, bfr[ni][0], acc[mi][ni], 0, 0, 0);
        acc[mi][ni] = __builtin_amdgcn_mfma_f32_16x16x32_bf16(a1, bfr[ni][1], acc[mi][ni], 0, 0, 0);
      }
    }
    __builtin_amdgcn_s_setprio(0);
    asm volatile("s_waitcnt vmcnt(0)" ::: "memory");  // next tile resident
    __builtin_amdgcn_s_barrier();                     // all waves done reading buf
    asm volatile("" ::: "memory");
    bufoff ^= 65536;
  }
#undef STG

  if (IS_UP) {
    // ---- epilogue: gelu -> bf16 -> LDS repack (2 passes of 64 rows) -> 16B row stores ----
    char* epi = lds + wid * 9216;  // 64 rows x 144B per wave
#pragma unroll
    for (int p = 0; p < 2; ++p) {
#pragma unroll
      for (int ni = 0; ni < 4; ++ni) {
        const float bv = bias[e * NDIM_ + tileN * 256 + wc * 64 + ni * 16 + fr];
#pragma unroll
        for (int mi2 = 0; mi2 < 4; ++mi2) {
          const int mi = p * 4 + mi2;
#pragma unroll
          for (int r = 0; r < 4; ++r) {
            float v = gelu_exact(acc[mi][ni][r] + bv);
            *(unsigned short*)(epi + (mi2 * 16 + kg * 4 + r) * 144 + (ni * 16 + fr) * 2) =
                (unsigned short)f2bf(v);
          }
        }
      }
      __builtin_amdgcn_s_barrier();
#pragma unroll
      for (int jj = 0; jj < 8; ++jj) {
        const int row = jj * 8 + (l >> 3);
        const int grow = tileM * 256 + wr * 128 + p * 64 + row;
        if (grow < count) {
          uint4 v = *(const uint4*)(epi + row * 144 + j8 * 16);
          *(uint4*)((char*)h_out +
                    ((size_t)(base + grow) * HDIM + tileN * 256 + wc * 64 + j8 * 8) * 2) = v;
        }
      }
      __builtin_amdgcn_s_barrier();
    }
  } else {
    const int colBase = tileN * 256 + wc * 64;
    float bdv[4];
#pragma unroll
    for (int ni = 0; ni < 4; ++ni) bdv[ni] = bias[e * NDIM_ + colBase + ni * 16 + fr];
#pragma unroll
    for (int mi = 0; mi < 8; ++mi) {
#pragma unroll
      for (int r = 0; r < 4; ++r) {
        const int sl = tileM * 256 + wr * 128 + mi * 16 + kg * 4 + r;
        if (sl < count) {
          const int idx = base + sl;
          const float gate = gate_list[idx];
          const int tok = tok_list[idx];
          float* orow = out + (size_t)tok * DDIM + colBase;
#pragma unroll
          for (int ni = 0; ni < 4; ++ni)
            atomicAdd(orow + ni * 16 + fr, (acc[mi][ni][r] + bdv[ni]) * gate);
        }
      }
    }
  }
}

// ---------------- host launcher ----------------
// Workspace ~113 MB:
//   [0, 16MB)        xb      (live: cast -> up_gemm)
//   [16MB, 48MB)     WuT     (live: transposeWu -> up_gemm)
//   [0, 32MB)        WdT     (written AFTER up_gemm, reuses xb+WuT region)
//   [48MB, 112.5MB)  h_ws    16512 rows x 2048 x bf16
//   [112.5MB, ...)   router/compaction lists + WgT/WnT
extern "C" void kernel_launch(void* const* d_in, const int* in_sizes, int n_in,
                              void* d_out, int out_size, void* d_ws, size_t ws_size,
                              hipStream_t stream) {
  const float* x     = (const float*)d_in[0];
  const float* noise = (const float*)d_in[1];
  const float* Wg    = (const float*)d_in[2];
  const float* bg    = (const float*)d_in[3];
  const float* Wn    = (const float*)d_in[4];
  const float* bn    = (const float*)d_in[5];
  const float* Wu    = (const float*)d_in[6];
  const float* bu    = (const float*)d_in[7];
  const float* Wd    = (const float*)d_in[8];
  const float* bd    = (const float*)d_in[9];
  float* out = (float*)d_out;
  char* ws = (char*)d_ws;

  unsigned short* xb  = (unsigned short*)(ws);                    // 16,777,216 B
  unsigned short* WuT = (unsigned short*)(ws + 16777216);         // 33,554,432 B
  unsigned short* WdT = (unsigned short*)(ws);                    // 33,554,432 B (reuse, after up_gemm)
  unsigned short* hws = (unsigned short*)(ws + 50331648);         // 67,633,152 B
  char* small = ws + 117964800;
  int*    e0e1      = (int*)(small);                              // 32,768 B
  float2* gg        = (float2*)(small + 32768);                   // 65,536 B
  int*    tok_list  = (int*)(small + 98304);                      // 65,536 B
  float*  gate_list = (float*)(small + 163840);                   // 65,536 B
  int*    counts    = (int*)(small + 229376);
  int*    bases     = (int*)(small + 229408);
  float*  WgT       = (float*)(small + 262144);                   // 32,768 B
  float*  WnT       = (float*)(small + 294912);                   // 32,768 B

  hipMemsetAsync(d_out, 0, (size_t)out_size * sizeof(float), stream);

  cast_x_kernel<<<4096, 256, 0, stream>>>((const float4*)x, (uint4*)xb);
  transpose_router_w<<<32, 256, 0, stream>>>(Wg, Wn, WgT, WnT);
  transpose_cast64<<<dim3(HDIM / 64, DDIM / 64, NE), 256, 0, stream>>>(Wu, WuT, DDIM, HDIM);
  router_kernel<<<T_TOK / 4, 256, 0, stream>>>(x, noise, WgT, bg, WnT, bn, e0e1, gg);
  compact_kernel<<<NE, 512, 0, stream>>>(e0e1, gg, tok_list, gate_list, counts, bases);
  moe_gemm256_2ph<true><<<dim3(HDIM / 256, 32, NE), 512, 0, stream>>>(
      xb, WuT, bu, tok_list, gate_list, counts, bases, hws, out);
  transpose_cast64<<<dim3(DDIM / 64, HDIM / 64, NE), 256, 0, stream>>>(Wd, WdT, HDIM, DDIM);
  moe_gemm256_2ph<false><<<dim3(DDIM / 256, 32, NE), 512, 0, stream>>>(
      hws, WdT, bd, tok_list, gate_list, counts, bases, hws, out);
}

// Round 10
// 451.171 us; speedup vs baseline: 1.0064x; 1.0064x over previous
//
#include <hip/hip_runtime.h>
#include <math.h>

#define T_TOK 8192
#define DDIM 1024
#define HDIM 2048
#define NE 8

typedef float f32x4 __attribute__((ext_vector_type(4)));
typedef short short8 __attribute__((ext_vector_type(8)));
typedef __attribute__((address_space(3))) char as3_char;
typedef __attribute__((address_space(1))) const char as1_cchar;

__device__ __forceinline__ unsigned f2bf(float f) {
  unsigned u = __float_as_uint(f);
  return (u + 0x7fffu + ((u >> 16) & 1u)) >> 16;
}
__device__ __forceinline__ float gelu_exact(float v) {
  return 0.5f * v * (1.0f + erff(v * 0.70710678118654752f));
}

// ---------------- cast x -> bf16 ----------------
__global__ void cast_x_kernel(const float4* __restrict__ x4, uint4* __restrict__ xb4) {
  int i = blockIdx.x * blockDim.x + threadIdx.x;
  float4 a = x4[2 * i], b = x4[2 * i + 1];
  uint4 o;
  o.x = f2bf(a.x) | (f2bf(a.y) << 16);
  o.y = f2bf(a.z) | (f2bf(a.w) << 16);
  o.z = f2bf(b.x) | (f2bf(b.y) << 16);
  o.w = f2bf(b.z) | (f2bf(b.w) << 16);
  xb4[i] = o;
}

// ---------------- transpose + cast: in [E][R][C] f32 -> out [E][C][R] bf16, 64x64 tiles ----
__global__ __launch_bounds__(256) void transpose_cast64(const float* __restrict__ in,
                                                        unsigned short* __restrict__ out,
                                                        int R, int C) {
  __shared__ float tile[64][65];
  size_t eoff = (size_t)blockIdx.z * R * C;
  const int r0 = blockIdx.y << 6, c0 = blockIdx.x << 6;
  const int tid = threadIdx.x;
  const int lr = tid >> 4;          // 0..15
  const int lc4 = (tid & 15) << 2;  // 0,4,..,60
#pragma unroll
  for (int rr = 0; rr < 4; ++rr) {
    int r = lr + rr * 16;
    float4 v = *(const float4*)(in + eoff + (size_t)(r0 + r) * C + c0 + lc4);
    tile[r][lc4] = v.x; tile[r][lc4 + 1] = v.y; tile[r][lc4 + 2] = v.z; tile[r][lc4 + 3] = v.w;
  }
  __syncthreads();
  const int c = tid >> 2;           // 0..63
  const int rch = (tid & 3) << 4;   // 0,16,32,48
  unsigned short tmp[16];
#pragma unroll
  for (int i = 0; i < 16; ++i) tmp[i] = (unsigned short)f2bf(tile[rch + i][c]);
  unsigned short* dst = out + eoff + (size_t)(c0 + c) * R + r0 + rch;
  *(uint4*)dst = *(const uint4*)tmp;
  *(uint4*)(dst + 8) = *(const uint4*)(tmp + 8);
}

// ---------------- transpose router weights: Wg/Wn [D][E] f32 -> [E][D] f32 ----------------
__global__ void transpose_router_w(const float* __restrict__ Wg, const float* __restrict__ Wn,
                                   float* __restrict__ WgT, float* __restrict__ WnT) {
  int i = blockIdx.x * 256 + threadIdx.x;  // over D*E = 8192
  int d = i >> 3, e = i & 7;
  WgT[e * DDIM + d] = Wg[i];
  WnT[e * DDIM + d] = Wn[i];
}

// ---------------- router: 4 tokens/block, 8-lane group per expert, fp64 dots ----------------
__global__ __launch_bounds__(256) void router_kernel(
    const float* __restrict__ x, const float* __restrict__ noise,
    const float* __restrict__ WgT, const float* __restrict__ bg,
    const float* __restrict__ WnT, const float* __restrict__ bn,
    int* __restrict__ e0e1, float2* __restrict__ gg) {
  const int wid = threadIdx.x >> 6, l = threadIdx.x & 63;
  const int t = blockIdx.x * 4 + wid;
  const int g = l >> 3, j = l & 7;
  const float4* xp = (const float4*)(x + (size_t)t * DDIM) + j * 32;
  const float4* wg = (const float4*)(WgT + (size_t)g * DDIM) + j * 32;
  const float4* wn = (const float4*)(WnT + (size_t)g * DDIM) + j * 32;
  double sg = 0.0, sn = 0.0;
#pragma unroll
  for (int i = 0; i < 32; ++i) {
    float4 xv = xp[i], a = wg[i], b = wn[i];
    sg += (double)xv.x * a.x + (double)xv.y * a.y + (double)xv.z * a.z + (double)xv.w * a.w;
    sn += (double)xv.x * b.x + (double)xv.y * b.y + (double)xv.z * b.z + (double)xv.w * b.w;
  }
#pragma unroll
  for (int off = 1; off < 8; off <<= 1) {
    sg += __shfl_xor(sg, off);
    sn += __shfl_xor(sn, off);
  }
  double nl = sn + (double)bn[g];
  double sp = (nl > 30.0) ? nl : log1p(exp(nl));
  double nv = sg + (double)bg[g] + (double)noise[(size_t)t * 8 + g] * sp;
  double nva[8];
#pragma unroll
  for (int e = 0; e < 8; ++e) nva[e] = __shfl(nv, e << 3);
  int i0 = 0;
  double v0 = nva[0];
#pragma unroll
  for (int e = 1; e < 8; ++e)
    if (nva[e] > v0) { v0 = nva[e]; i0 = e; }
  int i1 = (i0 == 0) ? 1 : 0;
  double v1 = nva[i0 == 0 ? 1 : 0];
#pragma unroll
  for (int e = 0; e < 8; ++e)
    if (e != i0 && nva[e] > v1) { v1 = nva[e]; i1 = e; }
  if (l == 0) {
    double w1 = exp(v1 - v0);
    double s = 1.0 + w1;
    e0e1[t] = i0 | (i1 << 8);
    gg[t] = make_float2((float)(1.0 / s), (float)(w1 / s));
  }
}

// ---------------- deterministic compaction: 8 blocks (1/expert), 8 waves each ----------------
__global__ __launch_bounds__(512) void compact_kernel(
    const int* __restrict__ e0e1, const float2* __restrict__ gg,
    int* __restrict__ tok_list, float* __restrict__ gate_list,
    int* __restrict__ counts, int* __restrict__ bases) {
  __shared__ int cmat[8][8];  // [wave][expert]
  const int e = blockIdx.x;
  const int wid = threadIdx.x >> 6, l = threadIdx.x & 63;
  const int t0w = wid * (T_TOK / 8);
  int c[8] = {0, 0, 0, 0, 0, 0, 0, 0};
  for (int i = 0; i < T_TOK / 8 / 64; ++i) {
    int p = e0e1[t0w + i * 64 + l];
    int ea = p & 255, eb = (p >> 8) & 255;
#pragma unroll
    for (int ee = 0; ee < 8; ++ee)
      c[ee] += __popcll(__ballot(ea == ee || eb == ee));
  }
  if (l == 0) {
#pragma unroll
    for (int ee = 0; ee < 8; ++ee) cmat[wid][ee] = c[ee];
  }
  __syncthreads();
  int base = 0;
  for (int ee = 0; ee < 8; ++ee) {
    if (ee < e) {
#pragma unroll
      for (int w = 0; w < 8; ++w) base += cmat[w][ee];
    }
  }
  int off = base;
#pragma unroll
  for (int w = 0; w < 8; ++w)
    if (w < wid) off += cmat[w][e];
  if (threadIdx.x == 0) {
    int tot = 0;
#pragma unroll
    for (int w = 0; w < 8; ++w) tot += cmat[w][e];
    counts[e] = tot;
    bases[e] = base;
  }
  for (int i = 0; i < T_TOK / 8 / 64; ++i) {
    int t = t0w + i * 64 + l;
    int p = e0e1[t];
    int ea = p & 255, eb = (p >> 8) & 255;
    int k = (ea == e) ? 0 : ((eb == e) ? 1 : -1);
    unsigned long long m = __ballot(k >= 0);
    if (k >= 0) {
      int pos = __popcll(m & ((1ull << l) - 1ull));
      float2 g = gg[t];
      tok_list[off + pos] = t;
      gate_list[off + pos] = (k == 0) ? g.x : g.y;
    }
    off += __popcll(m);
  }
}

// =====================================================================================
// m97-loop GEMM, widened M: 256x128 tile, BK=64, 4 waves (2Mx2N, 128x64 each = acc 8x4),
// single 48KB buffer, 2 barriers per K-step, 64 MFMA/wave/K-step,
// chunk^=(row&7) swizzle on BOTH gload-source and ds_read (involution).
// 48KB LDS -> 2 blocks/CU co-resident (TLP hides the vmcnt(0) drain).
// =====================================================================================

// ---------------- up GEMM: h = gelu(x_gathered @ Wu + bu) -> bf16 h_ws ----------------
__global__ __launch_bounds__(256, 2) void up_gemm_kernel(
    const unsigned short* __restrict__ xb, const unsigned short* __restrict__ WuT,
    const float* __restrict__ bu, const int* __restrict__ tok_list,
    const int* __restrict__ counts, const int* __restrict__ bases,
    unsigned short* __restrict__ h_ws) {
  const int e = blockIdx.z;
  const int count = counts[e];
  const int tileM = blockIdx.y;
  const int tileN = blockIdx.x;
  if (tileM * 256 >= count) return;
  const int base = bases[e];

  __shared__ char lds[49152];  // [0,32K) A 256x64 bf16 | [32K,48K) B 128x64

  const int tid = threadIdx.x;
  const int wid = tid >> 6, l = tid & 63;
  const int wr = wid >> 1, wc = wid & 1;
  const int srow8 = tid >> 3, j8 = tid & 7;
  const int cm1 = count - 1;

  const char* gA[8];
  const char* gB[4];
#pragma unroll
  for (int i = 0; i < 8; ++i) {
    int r = i * 32 + srow8;  // 0..255
    int tok = tok_list[base + min(tileM * 256 + r, cm1)];
    gA[i] = (const char*)xb + (size_t)tok * 2048 + ((j8 ^ (r & 7)) << 4);
  }
#pragma unroll
  for (int i = 0; i < 4; ++i) {
    int r = i * 32 + srow8;  // 0..127
    gB[i] = (const char*)WuT + ((size_t)e * HDIM * DDIM + (size_t)(tileN * 128 + r) * DDIM) * 2 +
            ((j8 ^ (r & 7)) << 4);
  }

  const int fr = l & 15, kg = l >> 4;
  int aoff[8][2], boff[4][2];
#pragma unroll
  for (int mi = 0; mi < 8; ++mi)
#pragma unroll
    for (int kk = 0; kk < 2; ++kk)
      aoff[mi][kk] = (wr * 128 + mi * 16 + fr) * 128 + ((((kk << 2) | kg) ^ (fr & 7)) << 4);
#pragma unroll
  for (int ni = 0; ni < 4; ++ni)
#pragma unroll
    for (int kk = 0; kk < 2; ++kk)
      boff[ni][kk] = 32768 + (wc * 64 + ni * 16 + fr) * 128 + ((((kk << 2) | kg) ^ (fr & 7)) << 4);

  f32x4 acc[8][4];
  const f32x4 zz = {0.f, 0.f, 0.f, 0.f};
#pragma unroll
  for (int mi = 0; mi < 8; ++mi)
#pragma unroll
    for (int ni = 0; ni < 4; ++ni) acc[mi][ni] = zz;

  for (int kt = 0; kt < 16; ++kt) {
    __builtin_amdgcn_s_barrier();  // all waves done reading previous tile
    asm volatile("" ::: "memory");
#pragma unroll
    for (int i = 0; i < 8; ++i)
      __builtin_amdgcn_global_load_lds((as1_cchar*)(gA[i] + kt * 128),
                                       (as3_char*)lds + i * 4096 + wid * 1024, 16, 0, 0);
#pragma unroll
    for (int i = 0; i < 4; ++i)
      __builtin_amdgcn_global_load_lds((as1_cchar*)(gB[i] + kt * 128),
                                       (as3_char*)lds + 32768 + i * 4096 + wid * 1024, 16, 0, 0);
    asm volatile("s_waitcnt vmcnt(0)" ::: "memory");
    __builtin_amdgcn_s_barrier();
    asm volatile("" ::: "memory");

    short8 bf[4][2];
#pragma unroll
    for (int ni = 0; ni < 4; ++ni) {
      bf[ni][0] = *(const short8*)(lds + boff[ni][0]);
      bf[ni][1] = *(const short8*)(lds + boff[ni][1]);
    }
    __builtin_amdgcn_s_setprio(1);
#pragma unroll
    for (int mi = 0; mi < 8; ++mi) {
      short8 a0 = *(const short8*)(lds + aoff[mi][0]);
      short8 a1 = *(const short8*)(lds + aoff[mi][1]);
#pragma unroll
      for (int ni = 0; ni < 4; ++ni) {
        acc[mi][ni] = __builtin_amdgcn_mfma_f32_16x16x32_bf16(a0, bf[ni][0], acc[mi][ni], 0, 0, 0);
        acc[mi][ni] = __builtin_amdgcn_mfma_f32_16x16x32_bf16(a1, bf[ni][1], acc[mi][ni], 0, 0, 0);
      }
    }
    __builtin_amdgcn_s_setprio(0);
  }

  // ---- epilogue: gelu -> bf16 -> LDS repack (2 passes of 64 rows) -> 16B row stores ----
  __builtin_amdgcn_s_barrier();
  asm volatile("" ::: "memory");
  char* epi = lds + wid * 9216;  // 64 rows x 144B per wave (4 waves = 36KB <= 48KB)
#pragma unroll
  for (int p = 0; p < 2; ++p) {
#pragma unroll
    for (int ni = 0; ni < 4; ++ni) {
      const float bv = bu[e * HDIM + tileN * 128 + wc * 64 + ni * 16 + fr];
#pragma unroll
      for (int mi2 = 0; mi2 < 4; ++mi2) {
        const int mi = p * 4 + mi2;
#pragma unroll
        for (int r = 0; r < 4; ++r) {
          float v = gelu_exact(acc[mi][ni][r] + bv);
          *(unsigned short*)(epi + (mi2 * 16 + kg * 4 + r) * 144 + (ni * 16 + fr) * 2) =
              (unsigned short)f2bf(v);
        }
      }
    }
    __builtin_amdgcn_s_barrier();
#pragma unroll
    for (int jj = 0; jj < 8; ++jj) {
      const int row = jj * 8 + (l >> 3);
      const int grow = tileM * 256 + wr * 128 + p * 64 + row;
      if (grow < count) {
        uint4 v = *(const uint4*)(epi + row * 144 + j8 * 16);
        *(uint4*)((char*)h_ws +
                  ((size_t)(base + grow) * HDIM + tileN * 128 + wc * 64 + j8 * 8) * 2) = v;
      }
    }
    __builtin_amdgcn_s_barrier();
  }
}

// ---------------- down GEMM: out += gate * (h @ Wd + bd), atomic scatter ----------------
__global__ __launch_bounds__(256, 2) void down_gemm_kernel(
    const unsigned short* __restrict__ h_ws, const unsigned short* __restrict__ WdT,
    const float* __restrict__ bd, const int* __restrict__ tok_list,
    const float* __restrict__ gate_list, const int* __restrict__ counts,
    const int* __restrict__ bases, float* __restrict__ out) {
  const int e = blockIdx.z;
  const int count = counts[e];
  const int tileM = blockIdx.y;
  const int tileN = blockIdx.x;
  if (tileM * 256 >= count) return;
  const int base = bases[e];

  __shared__ char lds[49152];

  const int tid = threadIdx.x;
  const int wid = tid >> 6, l = tid & 63;
  const int wr = wid >> 1, wc = wid & 1;
  const int srow8 = tid >> 3, j8 = tid & 7;
  const int cm1 = count - 1;

  const char* gA[8];
  const char* gB[4];
#pragma unroll
  for (int i = 0; i < 8; ++i) {
    int r = i * 32 + srow8;
    gA[i] = (const char*)h_ws + (size_t)(base + min(tileM * 256 + r, cm1)) * 4096 +
            ((j8 ^ (r & 7)) << 4);
  }
#pragma unroll
  for (int i = 0; i < 4; ++i) {
    int r = i * 32 + srow8;
    gB[i] = (const char*)WdT + ((size_t)e * DDIM * HDIM + (size_t)(tileN * 128 + r) * HDIM) * 2 +
            ((j8 ^ (r & 7)) << 4);
  }

  const int fr = l & 15, kg = l >> 4;
  int aoff[8][2], boff[4][2];
#pragma unroll
  for (int mi = 0; mi < 8; ++mi)
#pragma unroll
    for (int kk = 0; kk < 2; ++kk)
      aoff[mi][kk] = (wr * 128 + mi * 16 + fr) * 128 + ((((kk << 2) | kg) ^ (fr & 7)) << 4);
#pragma unroll
  for (int ni = 0; ni < 4; ++ni)
#pragma unroll
    for (int kk = 0; kk < 2; ++kk)
      boff[ni][kk] = 32768 + (wc * 64 + ni * 16 + fr) * 128 + ((((kk << 2) | kg) ^ (fr & 7)) << 4);

  f32x4 acc[8][4];
  const f32x4 zz = {0.f, 0.f, 0.f, 0.f};
#pragma unroll
  for (int mi = 0; mi < 8; ++mi)
#pragma unroll
    for (int ni = 0; ni < 4; ++ni) acc[mi][ni] = zz;

  for (int kt = 0; kt < 32; ++kt) {
    __builtin_amdgcn_s_barrier();
    asm volatile("" ::: "memory");
#pragma unroll
    for (int i = 0; i < 8; ++i)
      __builtin_amdgcn_global_load_lds((as1_cchar*)(gA[i] + kt * 128),
                                       (as3_char*)lds + i * 4096 + wid * 1024, 16, 0, 0);
#pragma unroll
    for (int i = 0; i < 4; ++i)
      __builtin_amdgcn_global_load_lds((as1_cchar*)(gB[i] + kt * 128),
                                       (as3_char*)lds + 32768 + i * 4096 + wid * 1024, 16, 0, 0);
    asm volatile("s_waitcnt vmcnt(0)" ::: "memory");
    __builtin_amdgcn_s_barrier();
    asm volatile("" ::: "memory");

    short8 bf[4][2];
#pragma unroll
    for (int ni = 0; ni < 4; ++ni) {
      bf[ni][0] = *(const short8*)(lds + boff[ni][0]);
      bf[ni][1] = *(const short8*)(lds + boff[ni][1]);
    }
    __builtin_amdgcn_s_setprio(1);
#pragma unroll
    for (int mi = 0; mi < 8; ++mi) {
      short8 a0 = *(const short8*)(lds + aoff[mi][0]);
      short8 a1 = *(const short8*)(lds + aoff[mi][1]);
#pragma unroll
      for (int ni = 0; ni < 4; ++ni) {
        acc[mi][ni] = __builtin_amdgcn_mfma_f32_16x16x32_bf16(a0, bf[ni][0], acc[mi][ni], 0, 0, 0);
        acc[mi][ni] = __builtin_amdgcn_mfma_f32_16x16x32_bf16(a1, bf[ni][1], acc[mi][ni], 0, 0, 0);
      }
    }
    __builtin_amdgcn_s_setprio(0);
  }

  const int colBase = tileN * 128 + wc * 64;
  float bdv[4];
#pragma unroll
  for (int ni = 0; ni < 4; ++ni) bdv[ni] = bd[e * DDIM + colBase + ni * 16 + fr];
#pragma unroll
  for (int mi = 0; mi < 8; ++mi) {
#pragma unroll
    for (int r = 0; r < 4; ++r) {
      const int sl = tileM * 256 + wr * 128 + mi * 16 + kg * 4 + r;
      if (sl < count) {
        const int idx = base + sl;
        const float gate = gate_list[idx];
        const int tok = tok_list[idx];
        float* orow = out + (size_t)tok * DDIM + colBase;
#pragma unroll
        for (int ni = 0; ni < 4; ++ni)
          atomicAdd(orow + ni * 16 + fr, (acc[mi][ni][r] + bdv[ni]) * gate);
      }
    }
  }
}

// ---------------- host launcher ----------------
// Workspace ~113 MB:
//   [0, 16MB)        xb      (live: cast -> up_gemm)
//   [16MB, 48MB)     WuT     (live: transposeWu -> up_gemm)
//   [0, 32MB)        WdT     (written AFTER up_gemm, reuses xb+WuT region)
//   [48MB, 112.5MB)  h_ws    16512 rows x 2048 x bf16
//   [112.5MB, ...)   router/compaction lists + WgT/WnT
extern "C" void kernel_launch(void* const* d_in, const int* in_sizes, int n_in,
                              void* d_out, int out_size, void* d_ws, size_t ws_size,
                              hipStream_t stream) {
  const float* x     = (const float*)d_in[0];
  const float* noise = (const float*)d_in[1];
  const float* Wg    = (const float*)d_in[2];
  const float* bg    = (const float*)d_in[3];
  const float* Wn    = (const float*)d_in[4];
  const float* bn    = (const float*)d_in[5];
  const float* Wu    = (const float*)d_in[6];
  const float* bu    = (const float*)d_in[7];
  const float* Wd    = (const float*)d_in[8];
  const float* bd    = (const float*)d_in[9];
  float* out = (float*)d_out;
  char* ws = (char*)d_ws;

  unsigned short* xb  = (unsigned short*)(ws);                    // 16,777,216 B
  unsigned short* WuT = (unsigned short*)(ws + 16777216);         // 33,554,432 B
  unsigned short* WdT = (unsigned short*)(ws);                    // 33,554,432 B (reuse, after up_gemm)
  unsigned short* hws = (unsigned short*)(ws + 50331648);         // 67,633,152 B
  char* small = ws + 117964800;
  int*    e0e1      = (int*)(small);                              // 32,768 B
  float2* gg        = (float2*)(small + 32768);                   // 65,536 B
  int*    tok_list  = (int*)(small + 98304);                      // 65,536 B
  float*  gate_list = (float*)(small + 163840);                   // 65,536 B
  int*    counts    = (int*)(small + 229376);
  int*    bases     = (int*)(small + 229408);
  float*  WgT       = (float*)(small + 262144);                   // 32,768 B
  float*  WnT       = (float*)(small + 294912);                   // 32,768 B

  hipMemsetAsync(d_out, 0, (size_t)out_size * sizeof(float), stream);

  cast_x_kernel<<<4096, 256, 0, stream>>>((const float4*)x, (uint4*)xb);
  transpose_router_w<<<32, 256, 0, stream>>>(Wg, Wn, WgT, WnT);
  transpose_cast64<<<dim3(HDIM / 64, DDIM / 64, NE), 256, 0, stream>>>(Wu, WuT, DDIM, HDIM);
  router_kernel<<<T_TOK / 4, 256, 0, stream>>>(x, noise, WgT, bg, WnT, bn, e0e1, gg);
  compact_kernel<<<NE, 512, 0, stream>>>(e0e1, gg, tok_list, gate_list, counts, bases);
  up_gemm_kernel<<<dim3(16, 32, NE), 256, 0, stream>>>(xb, WuT, bu, tok_list, counts, bases, hws);
  transpose_cast64<<<dim3(DDIM / 64, HDIM / 64, NE), 256, 0, stream>>>(Wd, WdT, HDIM, DDIM);
  down_gemm_kernel<<<dim3(8, 32, NE), 256, 0, stream>>>(hws, WdT, bd, tok_list, gate_list, counts, bases, out);
}

// Round 11
// 325.462 us; speedup vs baseline: 1.3952x; 1.3862x over previous
//
#include <hip/hip_runtime.h>
#include <math.h>

#define T_TOK 8192
#define DDIM 1024
#define HDIM 2048
#define NE 8

typedef float f32x4 __attribute__((ext_vector_type(4)));
typedef short short8 __attribute__((ext_vector_type(8)));
typedef __attribute__((address_space(3))) char as3_char;
typedef __attribute__((address_space(1))) const char as1_cchar;

__device__ __forceinline__ unsigned f2bf(float f) {
  unsigned u = __float_as_uint(f);
  return (u + 0x7fffu + ((u >> 16) & 1u)) >> 16;
}
__device__ __forceinline__ float gelu_exact(float v) {
  return 0.5f * v * (1.0f + erff(v * 0.70710678118654752f));
}

// ---------------- transpose + cast: in [E][R][C] f32 -> out [E][C][R] bf16, 64x64 tiles ----
__device__ __forceinline__ void transpose_body(const float* __restrict__ in,
                                               unsigned short* __restrict__ out,
                                               int R, int C, int e, int bx, int by,
                                               float (*tile)[65]) {
  size_t eoff = (size_t)e * R * C;
  const int r0 = by << 6, c0 = bx << 6;
  const int tid = threadIdx.x;
  const int lr = tid >> 4;          // 0..15
  const int lc4 = (tid & 15) << 2;  // 0,4,..,60
#pragma unroll
  for (int rr = 0; rr < 4; ++rr) {
    int r = lr + rr * 16;
    float4 v = *(const float4*)(in + eoff + (size_t)(r0 + r) * C + c0 + lc4);
    tile[r][lc4] = v.x; tile[r][lc4 + 1] = v.y; tile[r][lc4 + 2] = v.z; tile[r][lc4 + 3] = v.w;
  }
  __syncthreads();
  const int c = tid >> 2;           // 0..63
  const int rch = (tid & 3) << 4;   // 0,16,32,48
  unsigned short tmp[16];
#pragma unroll
  for (int i = 0; i < 16; ++i) tmp[i] = (unsigned short)f2bf(tile[rch + i][c]);
  unsigned short* dst = out + eoff + (size_t)(c0 + c) * R + r0 + rch;
  *(uint4*)dst = *(const uint4*)tmp;
  *(uint4*)(dst + 8) = *(const uint4*)(tmp + 8);
}

// standalone transpose kernel (used for Wd after up_gemm frees the workspace region)
__global__ __launch_bounds__(256) void transpose_cast64(const float* __restrict__ in,
                                                        unsigned short* __restrict__ out,
                                                        int R, int C) {
  __shared__ float tile[64][65];
  transpose_body(in, out, R, C, blockIdx.z, blockIdx.x, blockIdx.y, tile);
}

// ---------------- fused prep: cast_x | Wu-transpose | router (natural Wg/Wn) | zero-out ----
__global__ __launch_bounds__(256) void prep_kernel(
    const float* __restrict__ x, const float* __restrict__ noise,
    const float* __restrict__ Wg, const float* __restrict__ bg,
    const float* __restrict__ Wn, const float* __restrict__ bn,
    const float* __restrict__ Wu,
    unsigned short* __restrict__ xb, unsigned short* __restrict__ WuT,
    int* __restrict__ e0e1, float2* __restrict__ gg, float4* __restrict__ out4) {
  __shared__ float tile[64][65];
  const int id = blockIdx.x;
  const int tid = threadIdx.x;

  if (id < 4096) {
    // ---- cast x -> bf16 (96 MB traffic) ----
    const int i = id * 256 + tid;
    const float4* x4 = (const float4*)x;
    float4 a = x4[2 * i], b = x4[2 * i + 1];
    uint4 o;
    o.x = f2bf(a.x) | (f2bf(a.y) << 16);
    o.y = f2bf(a.z) | (f2bf(a.w) << 16);
    o.z = f2bf(b.x) | (f2bf(b.y) << 16);
    o.w = f2bf(b.z) | (f2bf(b.w) << 16);
    ((uint4*)xb)[i] = o;
  } else if (id < 8192) {
    // ---- Wu [E][D][H] -> WuT [E][H][D] bf16 ----
    const int t = id - 4096;
    const int e = t >> 9, rem = t & 511;
    transpose_body(Wu, WuT, DDIM, HDIM, e, rem & 31, rem >> 5, tile);
  } else if (id < 10240) {
    // ---- router: 4 tokens/block, wave per token, fp64 dots on NATURAL Wg/Wn ----
    const int wid = tid >> 6, l = tid & 63;
    const int t = (id - 8192) * 4 + wid;
    double lg[8] = {0, 0, 0, 0, 0, 0, 0, 0}, ln[8] = {0, 0, 0, 0, 0, 0, 0, 0};
    const float* xp = x + (size_t)t * DDIM;
#pragma unroll
    for (int i = 0; i < 16; ++i) {
      int d = i * 64 + l;
      float xv = xp[d];
      const float4* w4 = (const float4*)(Wg + d * 8);
      float4 wa = w4[0], wb = w4[1];
      lg[0] += (double)xv * wa.x; lg[1] += (double)xv * wa.y;
      lg[2] += (double)xv * wa.z; lg[3] += (double)xv * wa.w;
      lg[4] += (double)xv * wb.x; lg[5] += (double)xv * wb.y;
      lg[6] += (double)xv * wb.z; lg[7] += (double)xv * wb.w;
      const float4* n4 = (const float4*)(Wn + d * 8);
      float4 na = n4[0], nb = n4[1];
      ln[0] += (double)xv * na.x; ln[1] += (double)xv * na.y;
      ln[2] += (double)xv * na.z; ln[3] += (double)xv * na.w;
      ln[4] += (double)xv * nb.x; ln[5] += (double)xv * nb.y;
      ln[6] += (double)xv * nb.z; ln[7] += (double)xv * nb.w;
    }
#pragma unroll
    for (int e = 0; e < 8; ++e) {
#pragma unroll
      for (int off = 1; off < 64; off <<= 1) {
        lg[e] += __shfl_xor(lg[e], off);
        ln[e] += __shfl_xor(ln[e], off);
      }
    }
    // every lane now holds the full fp64 dot sums; compute redundantly, lane 0 writes
    double nv[8];
#pragma unroll
    for (int e = 0; e < 8; ++e) {
      double nl = ln[e] + (double)bn[e];
      double sp = (nl > 30.0) ? nl : log1p(exp(nl));
      nv[e] = lg[e] + (double)bg[e] + (double)noise[(size_t)t * 8 + e] * sp;
    }
    int i0 = 0;
    double v0 = nv[0];
#pragma unroll
    for (int e = 1; e < 8; ++e)
      if (nv[e] > v0) { v0 = nv[e]; i0 = e; }
    int i1 = (i0 == 0) ? 1 : 0;
    double v1 = nv[i0 == 0 ? 1 : 0];
#pragma unroll
    for (int e = 0; e < 8; ++e)
      if (e != i0 && nv[e] > v1) { v1 = nv[e]; i1 = e; }
    if (l == 0) {
      double w1 = exp(v1 - v0);
      double s = 1.0 + w1;
      e0e1[t] = i0 | (i1 << 8);
      gg[t] = make_float2((float)(1.0 / s), (float)(w1 / s));
    }
  } else {
    // ---- zero d_out (replaces hipMemsetAsync) ----
    const int b = (id - 10240) * 1024 + tid;
    const float4 z = {0.f, 0.f, 0.f, 0.f};
#pragma unroll
    for (int j = 0; j < 4; ++j) out4[b + j * 256] = z;
  }
}

// ---------------- deterministic compaction: 8 blocks (1/expert), 8 waves each ----------------
__global__ __launch_bounds__(512) void compact_kernel(
    const int* __restrict__ e0e1, const float2* __restrict__ gg,
    int* __restrict__ tok_list, float* __restrict__ gate_list,
    int* __restrict__ counts, int* __restrict__ bases) {
  __shared__ int cmat[8][8];  // [wave][expert]
  const int e = blockIdx.x;
  const int wid = threadIdx.x >> 6, l = threadIdx.x & 63;
  const int t0w = wid * (T_TOK / 8);
  int c[8] = {0, 0, 0, 0, 0, 0, 0, 0};
  for (int i = 0; i < T_TOK / 8 / 64; ++i) {
    int p = e0e1[t0w + i * 64 + l];
    int ea = p & 255, eb = (p >> 8) & 255;
#pragma unroll
    for (int ee = 0; ee < 8; ++ee)
      c[ee] += __popcll(__ballot(ea == ee || eb == ee));
  }
  if (l == 0) {
#pragma unroll
    for (int ee = 0; ee < 8; ++ee) cmat[wid][ee] = c[ee];
  }
  __syncthreads();
  int base = 0;
  for (int ee = 0; ee < 8; ++ee) {
    if (ee < e) {
#pragma unroll
      for (int w = 0; w < 8; ++w) base += cmat[w][ee];
    }
  }
  int off = base;
#pragma unroll
  for (int w = 0; w < 8; ++w)
    if (w < wid) off += cmat[w][e];
  if (threadIdx.x == 0) {
    int tot = 0;
#pragma unroll
    for (int w = 0; w < 8; ++w) tot += cmat[w][e];
    counts[e] = tot;
    bases[e] = base;
  }
  for (int i = 0; i < T_TOK / 8 / 64; ++i) {
    int t = t0w + i * 64 + l;
    int p = e0e1[t];
    int ea = p & 255, eb = (p >> 8) & 255;
    int k = (ea == e) ? 0 : ((eb == e) ? 1 : -1);
    unsigned long long m = __ballot(k >= 0);
    if (k >= 0) {
      int pos = __popcll(m & ((1ull << l) - 1ull));
      float2 g = gg[t];
      tok_list[off + pos] = t;
      gate_list[off + pos] = (k == 0) ? g.x : g.y;
    }
    off += __popcll(m);
  }
}

// =====================================================================================
// m97-structure GEMM (round-8 verified best): 128x128 tile, BK=64, 4 waves (2x2, 64x64),
// single 32KB buffer, 2 barriers per K-step, 32 MFMA/wave/K-step,
// chunk^=(row&7) swizzle on BOTH gload-source and ds_read (involution).
// =====================================================================================

// ---------------- up GEMM: h = gelu(x_gathered @ Wu + bu) -> bf16 h_ws ----------------
__global__ __launch_bounds__(256, 3) void up_gemm_kernel(
    const unsigned short* __restrict__ xb, const unsigned short* __restrict__ WuT,
    const float* __restrict__ bu, const int* __restrict__ tok_list,
    const int* __restrict__ counts, const int* __restrict__ bases,
    unsigned short* __restrict__ h_ws) {
  const int e = blockIdx.z;
  const int count = counts[e];
  const int tileM = blockIdx.y;
  const int tileN = blockIdx.x;
  if (tileM * 128 >= count) return;
  const int base = bases[e];

  __shared__ char lds[36864];  // [0,16K) A 128x64 bf16 | [16K,32K) B | epilogue reuses 36K

  const int tid = threadIdx.x;
  const int wid = tid >> 6, l = tid & 63;
  const int wr = wid >> 1, wc = wid & 1;
  const int lr = l >> 3, j8 = l & 7;
  const int kc = (j8 ^ lr) << 4;  // pre-swizzled global k-chunk byte (row&7 == lr)
  const int cm1 = count - 1;

  const char* gA[4];
  const char* gB[4];
#pragma unroll
  for (int i = 0; i < 4; ++i) {
    int row = wid * 8 + lr + i * 32;  // 0..127
    int tok = tok_list[base + min(tileM * 128 + row, cm1)];
    gA[i] = (const char*)xb + (size_t)tok * 2048 + kc;
    gB[i] = (const char*)WuT + ((size_t)e * HDIM * DDIM + (size_t)(tileN * 128 + row) * DDIM) * 2 + kc;
  }

  const int fr = l & 15, kg = l >> 4;
  int aoff[4][2], boff[4][2];
#pragma unroll
  for (int m = 0; m < 4; ++m)
#pragma unroll
    for (int kk = 0; kk < 2; ++kk)
      aoff[m][kk] = (wr * 64 + m * 16 + fr) * 128 + ((((kk << 2) | kg) ^ (fr & 7)) << 4);
#pragma unroll
  for (int n = 0; n < 4; ++n)
#pragma unroll
    for (int kk = 0; kk < 2; ++kk)
      boff[n][kk] = 16384 + (wc * 64 + n * 16 + fr) * 128 + ((((kk << 2) | kg) ^ (fr & 7)) << 4);

  f32x4 acc[4][4];
  const f32x4 zz = {0.f, 0.f, 0.f, 0.f};
#pragma unroll
  for (int m = 0; m < 4; ++m)
#pragma unroll
    for (int n = 0; n < 4; ++n) acc[m][n] = zz;

  for (int kt = 0; kt < 16; ++kt) {
    __builtin_amdgcn_s_barrier();  // all waves done reading previous tile
    asm volatile("" ::: "memory");
#pragma unroll
    for (int i = 0; i < 4; ++i)
      __builtin_amdgcn_global_load_lds((as1_cchar*)(gA[i] + kt * 128),
                                       (as3_char*)lds + wid * 1024 + i * 4096, 16, 0, 0);
#pragma unroll
    for (int i = 0; i < 4; ++i)
      __builtin_amdgcn_global_load_lds((as1_cchar*)(gB[i] + kt * 128),
                                       (as3_char*)lds + 16384 + wid * 1024 + i * 4096, 16, 0, 0);
    asm volatile("s_waitcnt vmcnt(0)" ::: "memory");
    __builtin_amdgcn_s_barrier();
    asm volatile("" ::: "memory");

    short8 bf[4][2];
#pragma unroll
    for (int n = 0; n < 4; ++n) {
      bf[n][0] = *(const short8*)(lds + boff[n][0]);
      bf[n][1] = *(const short8*)(lds + boff[n][1]);
    }
    __builtin_amdgcn_s_setprio(1);
#pragma unroll
    for (int m = 0; m < 4; ++m) {
      short8 a0 = *(const short8*)(lds + aoff[m][0]);
      short8 a1 = *(const short8*)(lds + aoff[m][1]);
#pragma unroll
      for (int n = 0; n < 4; ++n) {
        acc[m][n] = __builtin_amdgcn_mfma_f32_16x16x32_bf16(a0, bf[n][0], acc[m][n], 0, 0, 0);
        acc[m][n] = __builtin_amdgcn_mfma_f32_16x16x32_bf16(a1, bf[n][1], acc[m][n], 0, 0, 0);
      }
    }
    __builtin_amdgcn_s_setprio(0);
  }

  // ---- epilogue: gelu -> bf16 -> LDS (stride 144) -> coalesced 16B row stores ----
  __builtin_amdgcn_s_barrier();  // everyone done with GEMM LDS
  asm volatile("" ::: "memory");
  char* epi = lds + wid * 9216;  // 64 rows x 144B per wave
#pragma unroll
  for (int n = 0; n < 4; ++n) {
    const float bv = bu[e * HDIM + tileN * 128 + wc * 64 + n * 16 + fr];
#pragma unroll
    for (int m = 0; m < 4; ++m) {
#pragma unroll
      for (int r = 0; r < 4; ++r) {
        float v = gelu_exact(acc[m][n][r] + bv);
        *(unsigned short*)(epi + (m * 16 + kg * 4 + r) * 144 + (n * 16 + fr) * 2) =
            (unsigned short)f2bf(v);
      }
    }
  }
#pragma unroll
  for (int jj = 0; jj < 8; ++jj) {
    const int row = jj * 8 + lr;
    const int grow = tileM * 128 + wr * 64 + row;
    if (grow < count) {
      uint4 v = *(const uint4*)(epi + row * 144 + j8 * 16);
      *(uint4*)((char*)h_ws +
                ((size_t)(base + grow) * HDIM + tileN * 128 + wc * 64 + j8 * 8) * 2) = v;
    }
  }
}

// ---------------- down GEMM: out += gate * (h @ Wd + bd), atomic scatter ----------------
__global__ __launch_bounds__(256, 3) void down_gemm_kernel(
    const unsigned short* __restrict__ h_ws, const unsigned short* __restrict__ WdT,
    const float* __restrict__ bd, const int* __restrict__ tok_list,
    const float* __restrict__ gate_list, const int* __restrict__ counts,
    const int* __restrict__ bases, float* __restrict__ out) {
  const int e = blockIdx.z;
  const int count = counts[e];
  const int tileM = blockIdx.y;
  const int tileN = blockIdx.x;
  if (tileM * 128 >= count) return;
  const int base = bases[e];

  __shared__ char lds[32768];

  const int tid = threadIdx.x;
  const int wid = tid >> 6, l = tid & 63;
  const int wr = wid >> 1, wc = wid & 1;
  const int lr = l >> 3, j8 = l & 7;
  const int kc = (j8 ^ lr) << 4;
  const int cm1 = count - 1;

  const char* gA[4];
  const char* gB[4];
#pragma unroll
  for (int i = 0; i < 4; ++i) {
    int row = wid * 8 + lr + i * 32;
    gA[i] = (const char*)h_ws + (size_t)(base + min(tileM * 128 + row, cm1)) * 4096 + kc;
    gB[i] = (const char*)WdT + ((size_t)e * DDIM * HDIM + (size_t)(tileN * 128 + row) * HDIM) * 2 + kc;
  }

  const int fr = l & 15, kg = l >> 4;
  int aoff[4][2], boff[4][2];
#pragma unroll
  for (int m = 0; m < 4; ++m)
#pragma unroll
    for (int kk = 0; kk < 2; ++kk)
      aoff[m][kk] = (wr * 64 + m * 16 + fr) * 128 + ((((kk << 2) | kg) ^ (fr & 7)) << 4);
#pragma unroll
  for (int n = 0; n < 4; ++n)
#pragma unroll
    for (int kk = 0; kk < 2; ++kk)
      boff[n][kk] = 16384 + (wc * 64 + n * 16 + fr) * 128 + ((((kk << 2) | kg) ^ (fr & 7)) << 4);

  f32x4 acc[4][4];
  const f32x4 zz = {0.f, 0.f, 0.f, 0.f};
#pragma unroll
  for (int m = 0; m < 4; ++m)
#pragma unroll
    for (int n = 0; n < 4; ++n) acc[m][n] = zz;

  for (int kt = 0; kt < 32; ++kt) {
    __builtin_amdgcn_s_barrier();
    asm volatile("" ::: "memory");
#pragma unroll
    for (int i = 0; i < 4; ++i)
      __builtin_amdgcn_global_load_lds((as1_cchar*)(gA[i] + kt * 128),
                                       (as3_char*)lds + wid * 1024 + i * 4096, 16, 0, 0);
#pragma unroll
    for (int i = 0; i < 4; ++i)
      __builtin_amdgcn_global_load_lds((as1_cchar*)(gB[i] + kt * 128),
                                       (as3_char*)lds + 16384 + wid * 1024 + i * 4096, 16, 0, 0);
    asm volatile("s_waitcnt vmcnt(0)" ::: "memory");
    __builtin_amdgcn_s_barrier();
    asm volatile("" ::: "memory");

    short8 bf[4][2];
#pragma unroll
    for (int n = 0; n < 4; ++n) {
      bf[n][0] = *(const short8*)(lds + boff[n][0]);
      bf[n][1] = *(const short8*)(lds + boff[n][1]);
    }
    __builtin_amdgcn_s_setprio(1);
#pragma unroll
    for (int m = 0; m < 4; ++m) {
      short8 a0 = *(const short8*)(lds + aoff[m][0]);
      short8 a1 = *(const short8*)(lds + aoff[m][1]);
#pragma unroll
      for (int n = 0; n < 4; ++n) {
        acc[m][n] = __builtin_amdgcn_mfma_f32_16x16x32_bf16(a0, bf[n][0], acc[m][n], 0, 0, 0);
        acc[m][n] = __builtin_amdgcn_mfma_f32_16x16x32_bf16(a1, bf[n][1], acc[m][n], 0, 0, 0);
      }
    }
    __builtin_amdgcn_s_setprio(0);
  }

  const int colBase = tileN * 128;
  float bdv[4];
#pragma unroll
  for (int n = 0; n < 4; ++n) bdv[n] = bd[e * DDIM + colBase + wc * 64 + n * 16 + fr];
#pragma unroll
  for (int m = 0; m < 4; ++m) {
#pragma unroll
    for (int r = 0; r < 4; ++r) {
      const int sl = tileM * 128 + wr * 64 + m * 16 + kg * 4 + r;
      if (sl < count) {
        const int idx = base + sl;
        const float gate = gate_list[idx];
        const int tok = tok_list[idx];
        float* orow = out + (size_t)tok * DDIM + colBase;
#pragma unroll
        for (int n = 0; n < 4; ++n) {
          const int col = wc * 64 + n * 16 + fr;
          atomicAdd(orow + col, (acc[m][n][r] + bdv[n]) * gate);
        }
      }
    }
  }
}

// ---------------- host launcher ----------------
// Workspace ~113 MB:
//   [0, 16MB)        xb      (live: prep -> up_gemm)
//   [16MB, 48MB)     WuT     (live: prep -> up_gemm)
//   [0, 32MB)        WdT     (written AFTER up_gemm, reuses xb+WuT region)
//   [48MB, 112.5MB)  h_ws    16512 rows x 2048 x bf16
//   [112.5MB, ...)   router/compaction lists
extern "C" void kernel_launch(void* const* d_in, const int* in_sizes, int n_in,
                              void* d_out, int out_size, void* d_ws, size_t ws_size,
                              hipStream_t stream) {
  const float* x     = (const float*)d_in[0];
  const float* noise = (const float*)d_in[1];
  const float* Wg    = (const float*)d_in[2];
  const float* bg    = (const float*)d_in[3];
  const float* Wn    = (const float*)d_in[4];
  const float* bn    = (const float*)d_in[5];
  const float* Wu    = (const float*)d_in[6];
  const float* bu    = (const float*)d_in[7];
  const float* Wd    = (const float*)d_in[8];
  const float* bd    = (const float*)d_in[9];
  float* out = (float*)d_out;
  char* ws = (char*)d_ws;

  unsigned short* xb  = (unsigned short*)(ws);                    // 16,777,216 B
  unsigned short* WuT = (unsigned short*)(ws + 16777216);         // 33,554,432 B
  unsigned short* WdT = (unsigned short*)(ws);                    // 33,554,432 B (reuse, after up_gemm)
  unsigned short* hws = (unsigned short*)(ws + 50331648);         // 67,633,152 B
  char* small = ws + 117964800;
  int*    e0e1      = (int*)(small);                              // 32,768 B
  float2* gg        = (float2*)(small + 32768);                   // 65,536 B
  int*    tok_list  = (int*)(small + 98304);                      // 65,536 B
  float*  gate_list = (float*)(small + 163840);                   // 65,536 B
  int*    counts    = (int*)(small + 229376);
  int*    bases     = (int*)(small + 229408);

  // prep: 4096 cast_x + 4096 trWu + 2048 router + 2048 zero-out = 12288 blocks
  prep_kernel<<<12288, 256, 0, stream>>>(x, noise, Wg, bg, Wn, bn, Wu,
                                         xb, WuT, e0e1, gg, (float4*)out);
  compact_kernel<<<NE, 512, 0, stream>>>(e0e1, gg, tok_list, gate_list, counts, bases);
  up_gemm_kernel<<<dim3(16, 64, NE), 256, 0, stream>>>(xb, WuT, bu, tok_list, counts, bases, hws);
  transpose_cast64<<<dim3(DDIM / 64, HDIM / 64, NE), 256, 0, stream>>>(Wd, WdT, HDIM, DDIM);
  down_gemm_kernel<<<dim3(8, 64, NE), 256, 0, stream>>>(hws, WdT, bd, tok_list, gate_list, counts, bases, out);
}

// Round 12
// 319.736 us; speedup vs baseline: 1.4202x; 1.0179x over previous
//
#include <hip/hip_runtime.h>
#include <math.h>

#define T_TOK 8192
#define DDIM 1024
#define HDIM 2048
#define NE 8

typedef float f32x4 __attribute__((ext_vector_type(4)));
typedef short short8 __attribute__((ext_vector_type(8)));
typedef __attribute__((address_space(3))) char as3_char;
typedef __attribute__((address_space(1))) const char as1_cchar;

__device__ __forceinline__ unsigned f2bf(float f) {
  unsigned u = __float_as_uint(f);
  return (u + 0x7fffu + ((u >> 16) & 1u)) >> 16;
}
__device__ __forceinline__ float gelu_exact(float v) {
  return 0.5f * v * (1.0f + erff(v * 0.70710678118654752f));
}

// ---------------- transpose + cast: in [E][R][C] f32 -> out [E][C][R] bf16, 64x64 tiles ----
__device__ __forceinline__ void transpose_body(const float* __restrict__ in,
                                               unsigned short* __restrict__ out,
                                               int R, int C, int e, int bx, int by,
                                               float (*tile)[65]) {
  size_t eoff = (size_t)e * R * C;
  const int r0 = by << 6, c0 = bx << 6;
  const int tid = threadIdx.x;
  const int lr = tid >> 4;          // 0..15
  const int lc4 = (tid & 15) << 2;  // 0,4,..,60
#pragma unroll
  for (int rr = 0; rr < 4; ++rr) {
    int r = lr + rr * 16;
    float4 v = *(const float4*)(in + eoff + (size_t)(r0 + r) * C + c0 + lc4);
    tile[r][lc4] = v.x; tile[r][lc4 + 1] = v.y; tile[r][lc4 + 2] = v.z; tile[r][lc4 + 3] = v.w;
  }
  __syncthreads();
  const int c = tid >> 2;           // 0..63
  const int rch = (tid & 3) << 4;   // 0,16,32,48
  unsigned short tmp[16];
#pragma unroll
  for (int i = 0; i < 16; ++i) tmp[i] = (unsigned short)f2bf(tile[rch + i][c]);
  unsigned short* dst = out + eoff + (size_t)(c0 + c) * R + r0 + rch;
  *(uint4*)dst = *(const uint4*)tmp;
  *(uint4*)(dst + 8) = *(const uint4*)(tmp + 8);
}

// standalone transpose kernel (fallback path: Wd after up_gemm frees the region)
__global__ __launch_bounds__(256) void transpose_cast64(const float* __restrict__ in,
                                                        unsigned short* __restrict__ out,
                                                        int R, int C) {
  __shared__ float tile[64][65];
  transpose_body(in, out, R, C, blockIdx.z, blockIdx.x, blockIdx.y, tile);
}

// ---------------- fused prep: cast_x | Wu-transpose | router | zero-out | [Wd-transpose] ----
__global__ __launch_bounds__(256) void prep_kernel(
    const float* __restrict__ x, const float* __restrict__ noise,
    const float* __restrict__ Wg, const float* __restrict__ bg,
    const float* __restrict__ Wn, const float* __restrict__ bn,
    const float* __restrict__ Wu, const float* __restrict__ Wd,
    unsigned short* __restrict__ xb, unsigned short* __restrict__ WuT,
    unsigned short* __restrict__ WdT,
    int* __restrict__ e0e1, float2* __restrict__ gg, float4* __restrict__ out4) {
  __shared__ float tile[64][65];
  const int id = blockIdx.x;
  const int tid = threadIdx.x;

  if (id < 4096) {
    // ---- cast x -> bf16 ----
    const int i = id * 256 + tid;
    const float4* x4 = (const float4*)x;
    float4 a = x4[2 * i], b = x4[2 * i + 1];
    uint4 o;
    o.x = f2bf(a.x) | (f2bf(a.y) << 16);
    o.y = f2bf(a.z) | (f2bf(a.w) << 16);
    o.z = f2bf(b.x) | (f2bf(b.y) << 16);
    o.w = f2bf(b.z) | (f2bf(b.w) << 16);
    ((uint4*)xb)[i] = o;
  } else if (id < 8192) {
    // ---- Wu [E][D][H] -> WuT [E][H][D] bf16 ----
    const int t = id - 4096;
    const int e = t >> 9, rem = t & 511;
    transpose_body(Wu, WuT, DDIM, HDIM, e, rem & 31, rem >> 5, tile);
  } else if (id < 10240) {
    // ---- router: 4 tokens/block, wave per token, fp64 dots on NATURAL Wg/Wn ----
    const int wid = tid >> 6, l = tid & 63;
    const int t = (id - 8192) * 4 + wid;
    double lg[8] = {0, 0, 0, 0, 0, 0, 0, 0}, ln[8] = {0, 0, 0, 0, 0, 0, 0, 0};
    const float* xp = x + (size_t)t * DDIM;
#pragma unroll
    for (int i = 0; i < 16; ++i) {
      int d = i * 64 + l;
      float xv = xp[d];
      const float4* w4 = (const float4*)(Wg + d * 8);
      float4 wa = w4[0], wb = w4[1];
      lg[0] += (double)xv * wa.x; lg[1] += (double)xv * wa.y;
      lg[2] += (double)xv * wa.z; lg[3] += (double)xv * wa.w;
      lg[4] += (double)xv * wb.x; lg[5] += (double)xv * wb.y;
      lg[6] += (double)xv * wb.z; lg[7] += (double)xv * wb.w;
      const float4* n4 = (const float4*)(Wn + d * 8);
      float4 na = n4[0], nb = n4[1];
      ln[0] += (double)xv * na.x; ln[1] += (double)xv * na.y;
      ln[2] += (double)xv * na.z; ln[3] += (double)xv * na.w;
      ln[4] += (double)xv * nb.x; ln[5] += (double)xv * nb.y;
      ln[6] += (double)xv * nb.z; ln[7] += (double)xv * nb.w;
    }
#pragma unroll
    for (int e = 0; e < 8; ++e) {
#pragma unroll
      for (int off = 1; off < 64; off <<= 1) {
        lg[e] += __shfl_xor(lg[e], off);
        ln[e] += __shfl_xor(ln[e], off);
      }
    }
    double nv[8];
#pragma unroll
    for (int e = 0; e < 8; ++e) {
      double nl = ln[e] + (double)bn[e];
      double sp = (nl > 30.0) ? nl : log1p(exp(nl));
      nv[e] = lg[e] + (double)bg[e] + (double)noise[(size_t)t * 8 + e] * sp;
    }
    int i0 = 0;
    double v0 = nv[0];
#pragma unroll
    for (int e = 1; e < 8; ++e)
      if (nv[e] > v0) { v0 = nv[e]; i0 = e; }
    int i1 = (i0 == 0) ? 1 : 0;
    double v1 = nv[i0 == 0 ? 1 : 0];
#pragma unroll
    for (int e = 0; e < 8; ++e)
      if (e != i0 && nv[e] > v1) { v1 = nv[e]; i1 = e; }
    if (l == 0) {
      double w1 = exp(v1 - v0);
      double s = 1.0 + w1;
      e0e1[t] = i0 | (i1 << 8);
      gg[t] = make_float2((float)(1.0 / s), (float)(w1 / s));
    }
  } else if (id < 12288) {
    // ---- zero d_out (replaces hipMemsetAsync) ----
    const int b = (id - 10240) * 1024 + tid;
    const float4 z = {0.f, 0.f, 0.f, 0.f};
#pragma unroll
    for (int j = 0; j < 4; ++j) out4[b + j * 256] = z;
  } else {
    // ---- Wd [E][H][D] -> WdT [E][D][H] bf16 (only launched in big-workspace layout) ----
    const int t = id - 12288;
    const int e = t >> 9, rem = t & 511;
    transpose_body(Wd, WdT, HDIM, DDIM, e, rem & 15, rem >> 4, tile);
  }
}

// ---------------- deterministic compaction: 8 blocks (1/expert), 8 waves each ----------------
__global__ __launch_bounds__(512) void compact_kernel(
    const int* __restrict__ e0e1, const float2* __restrict__ gg,
    int* __restrict__ tok_list, float* __restrict__ gate_list,
    int* __restrict__ counts, int* __restrict__ bases) {
  __shared__ int cmat[8][8];  // [wave][expert]
  const int e = blockIdx.x;
  const int wid = threadIdx.x >> 6, l = threadIdx.x & 63;
  const int t0w = wid * (T_TOK / 8);
  int c[8] = {0, 0, 0, 0, 0, 0, 0, 0};
  for (int i = 0; i < T_TOK / 8 / 64; ++i) {
    int p = e0e1[t0w + i * 64 + l];
    int ea = p & 255, eb = (p >> 8) & 255;
#pragma unroll
    for (int ee = 0; ee < 8; ++ee)
      c[ee] += __popcll(__ballot(ea == ee || eb == ee));
  }
  if (l == 0) {
#pragma unroll
    for (int ee = 0; ee < 8; ++ee) cmat[wid][ee] = c[ee];
  }
  __syncthreads();
  int base = 0;
  for (int ee = 0; ee < 8; ++ee) {
    if (ee < e) {
#pragma unroll
      for (int w = 0; w < 8; ++w) base += cmat[w][ee];
    }
  }
  int off = base;
#pragma unroll
  for (int w = 0; w < 8; ++w)
    if (w < wid) off += cmat[w][e];
  if (threadIdx.x == 0) {
    int tot = 0;
#pragma unroll
    for (int w = 0; w < 8; ++w) tot += cmat[w][e];
    counts[e] = tot;
    bases[e] = base;
  }
  for (int i = 0; i < T_TOK / 8 / 64; ++i) {
    int t = t0w + i * 64 + l;
    int p = e0e1[t];
    int ea = p & 255, eb = (p >> 8) & 255;
    int k = (ea == e) ? 0 : ((eb == e) ? 1 : -1);
    unsigned long long m = __ballot(k >= 0);
    if (k >= 0) {
      int pos = __popcll(m & ((1ull << l) - 1ull));
      float2 g = gg[t];
      tok_list[off + pos] = t;
      gate_list[off + pos] = (k == 0) ? g.x : g.y;
    }
    off += __popcll(m);
  }
}

// =====================================================================================
// m97-structure GEMM (round-8 verified best): 128x128 tile, BK=64, 4 waves (2x2, 64x64),
// single 32KB buffer, 2 barriers per K-step, 32 MFMA/wave/K-step,
// chunk^=(row&7) swizzle on BOTH gload-source and ds_read (involution).
// =====================================================================================

// ---------------- up GEMM: h = gelu(x_gathered @ Wu + bu) -> bf16 h_ws ----------------
__global__ __launch_bounds__(256, 3) void up_gemm_kernel(
    const unsigned short* __restrict__ xb, const unsigned short* __restrict__ WuT,
    const float* __restrict__ bu, const int* __restrict__ tok_list,
    const int* __restrict__ counts, const int* __restrict__ bases,
    unsigned short* __restrict__ h_ws) {
  const int e = blockIdx.z;
  const int count = counts[e];
  const int tileM = blockIdx.y;
  const int tileN = blockIdx.x;
  if (tileM * 128 >= count) return;
  const int base = bases[e];

  __shared__ char lds[36864];  // [0,16K) A 128x64 bf16 | [16K,32K) B | epilogue reuses 36K

  const int tid = threadIdx.x;
  const int wid = tid >> 6, l = tid & 63;
  const int wr = wid >> 1, wc = wid & 1;
  const int lr = l >> 3, j8 = l & 7;
  const int kc = (j8 ^ lr) << 4;  // pre-swizzled global k-chunk byte (row&7 == lr)
  const int cm1 = count - 1;

  const char* gA[4];
  const char* gB[4];
#pragma unroll
  for (int i = 0; i < 4; ++i) {
    int row = wid * 8 + lr + i * 32;  // 0..127
    int tok = tok_list[base + min(tileM * 128 + row, cm1)];
    gA[i] = (const char*)xb + (size_t)tok * 2048 + kc;
    gB[i] = (const char*)WuT + ((size_t)e * HDIM * DDIM + (size_t)(tileN * 128 + row) * DDIM) * 2 + kc;
  }

  const int fr = l & 15, kg = l >> 4;
  int aoff[4][2], boff[4][2];
#pragma unroll
  for (int m = 0; m < 4; ++m)
#pragma unroll
    for (int kk = 0; kk < 2; ++kk)
      aoff[m][kk] = (wr * 64 + m * 16 + fr) * 128 + ((((kk << 2) | kg) ^ (fr & 7)) << 4);
#pragma unroll
  for (int n = 0; n < 4; ++n)
#pragma unroll
    for (int kk = 0; kk < 2; ++kk)
      boff[n][kk] = 16384 + (wc * 64 + n * 16 + fr) * 128 + ((((kk << 2) | kg) ^ (fr & 7)) << 4);

  f32x4 acc[4][4];
  const f32x4 zz = {0.f, 0.f, 0.f, 0.f};
#pragma unroll
  for (int m = 0; m < 4; ++m)
#pragma unroll
    for (int n = 0; n < 4; ++n) acc[m][n] = zz;

  for (int kt = 0; kt < 16; ++kt) {
    __builtin_amdgcn_s_barrier();  // all waves done reading previous tile
    asm volatile("" ::: "memory");
#pragma unroll
    for (int i = 0; i < 4; ++i)
      __builtin_amdgcn_global_load_lds((as1_cchar*)(gA[i] + kt * 128),
                                       (as3_char*)lds + wid * 1024 + i * 4096, 16, 0, 0);
#pragma unroll
    for (int i = 0; i < 4; ++i)
      __builtin_amdgcn_global_load_lds((as1_cchar*)(gB[i] + kt * 128),
                                       (as3_char*)lds + 16384 + wid * 1024 + i * 4096, 16, 0, 0);
    asm volatile("s_waitcnt vmcnt(0)" ::: "memory");
    __builtin_amdgcn_s_barrier();
    asm volatile("" ::: "memory");

    short8 bf[4][2];
#pragma unroll
    for (int n = 0; n < 4; ++n) {
      bf[n][0] = *(const short8*)(lds + boff[n][0]);
      bf[n][1] = *(const short8*)(lds + boff[n][1]);
    }
    __builtin_amdgcn_s_setprio(1);
#pragma unroll
    for (int m = 0; m < 4; ++m) {
      short8 a0 = *(const short8*)(lds + aoff[m][0]);
      short8 a1 = *(const short8*)(lds + aoff[m][1]);
#pragma unroll
      for (int n = 0; n < 4; ++n) {
        acc[m][n] = __builtin_amdgcn_mfma_f32_16x16x32_bf16(a0, bf[n][0], acc[m][n], 0, 0, 0);
        acc[m][n] = __builtin_amdgcn_mfma_f32_16x16x32_bf16(a1, bf[n][1], acc[m][n], 0, 0, 0);
      }
    }
    __builtin_amdgcn_s_setprio(0);
  }

  // ---- epilogue: gelu -> bf16 -> LDS (stride 144) -> coalesced 16B row stores ----
  __builtin_amdgcn_s_barrier();  // everyone done with GEMM LDS
  asm volatile("" ::: "memory");
  char* epi = lds + wid * 9216;  // 64 rows x 144B per wave
#pragma unroll
  for (int n = 0; n < 4; ++n) {
    const float bv = bu[e * HDIM + tileN * 128 + wc * 64 + n * 16 + fr];
#pragma unroll
    for (int m = 0; m < 4; ++m) {
#pragma unroll
      for (int r = 0; r < 4; ++r) {
        float v = gelu_exact(acc[m][n][r] + bv);
        *(unsigned short*)(epi + (m * 16 + kg * 4 + r) * 144 + (n * 16 + fr) * 2) =
            (unsigned short)f2bf(v);
      }
    }
  }
#pragma unroll
  for (int jj = 0; jj < 8; ++jj) {
    const int row = jj * 8 + lr;
    const int grow = tileM * 128 + wr * 64 + row;
    if (grow < count) {
      uint4 v = *(const uint4*)(epi + row * 144 + j8 * 16);
      *(uint4*)((char*)h_ws +
                ((size_t)(base + grow) * HDIM + tileN * 128 + wc * 64 + j8 * 8) * 2) = v;
    }
  }
}

// ---------------- down GEMM: out += gate * (h @ Wd + bd), atomic scatter ----------------
__global__ __launch_bounds__(256, 3) void down_gemm_kernel(
    const unsigned short* __restrict__ h_ws, const unsigned short* __restrict__ WdT,
    const float* __restrict__ bd, const int* __restrict__ tok_list,
    const float* __restrict__ gate_list, const int* __restrict__ counts,
    const int* __restrict__ bases, float* __restrict__ out) {
  const int e = blockIdx.z;
  const int count = counts[e];
  const int tileM = blockIdx.y;
  const int tileN = blockIdx.x;
  if (tileM * 128 >= count) return;
  const int base = bases[e];

  __shared__ char lds[32768];

  const int tid = threadIdx.x;
  const int wid = tid >> 6, l = tid & 63;
  const int wr = wid >> 1, wc = wid & 1;
  const int lr = l >> 3, j8 = l & 7;
  const int kc = (j8 ^ lr) << 4;
  const int cm1 = count - 1;

  const char* gA[4];
  const char* gB[4];
#pragma unroll
  for (int i = 0; i < 4; ++i) {
    int row = wid * 8 + lr + i * 32;
    gA[i] = (const char*)h_ws + (size_t)(base + min(tileM * 128 + row, cm1)) * 4096 + kc;
    gB[i] = (const char*)WdT + ((size_t)e * DDIM * HDIM + (size_t)(tileN * 128 + row) * HDIM) * 2 + kc;
  }

  const int fr = l & 15, kg = l >> 4;
  int aoff[4][2], boff[4][2];
#pragma unroll
  for (int m = 0; m < 4; ++m)
#pragma unroll
    for (int kk = 0; kk < 2; ++kk)
      aoff[m][kk] = (wr * 64 + m * 16 + fr) * 128 + ((((kk << 2) | kg) ^ (fr & 7)) << 4);
#pragma unroll
  for (int n = 0; n < 4; ++n)
#pragma unroll
    for (int kk = 0; kk < 2; ++kk)
      boff[n][kk] = 16384 + (wc * 64 + n * 16 + fr) * 128 + ((((kk << 2) | kg) ^ (fr & 7)) << 4);

  f32x4 acc[4][4];
  const f32x4 zz = {0.f, 0.f, 0.f, 0.f};
#pragma unroll
  for (int m = 0; m < 4; ++m)
#pragma unroll
    for (int n = 0; n < 4; ++n) acc[m][n] = zz;

  for (int kt = 0; kt < 32; ++kt) {
    __builtin_amdgcn_s_barrier();
    asm volatile("" ::: "memory");
#pragma unroll
    for (int i = 0; i < 4; ++i)
      __builtin_amdgcn_global_load_lds((as1_cchar*)(gA[i] + kt * 128),
                                       (as3_char*)lds + wid * 1024 + i * 4096, 16, 0, 0);
#pragma unroll
    for (int i = 0; i < 4; ++i)
      __builtin_amdgcn_global_load_lds((as1_cchar*)(gB[i] + kt * 128),
                                       (as3_char*)lds + 16384 + wid * 1024 + i * 4096, 16, 0, 0);
    asm volatile("s_waitcnt vmcnt(0)" ::: "memory");
    __builtin_amdgcn_s_barrier();
    asm volatile("" ::: "memory");

    short8 bf[4][2];
#pragma unroll
    for (int n = 0; n < 4; ++n) {
      bf[n][0] = *(const short8*)(lds + boff[n][0]);
      bf[n][1] = *(const short8*)(lds + boff[n][1]);
    }
    __builtin_amdgcn_s_setprio(1);
#pragma unroll
    for (int m = 0; m < 4; ++m) {
      short8 a0 = *(const short8*)(lds + aoff[m][0]);
      short8 a1 = *(const short8*)(lds + aoff[m][1]);
#pragma unroll
      for (int n = 0; n < 4; ++n) {
        acc[m][n] = __builtin_amdgcn_mfma_f32_16x16x32_bf16(a0, bf[n][0], acc[m][n], 0, 0, 0);
        acc[m][n] = __builtin_amdgcn_mfma_f32_16x16x32_bf16(a1, bf[n][1], acc[m][n], 0, 0, 0);
      }
    }
    __builtin_amdgcn_s_setprio(0);
  }

  const int colBase = tileN * 128;
  float bdv[4];
#pragma unroll
  for (int n = 0; n < 4; ++n) bdv[n] = bd[e * DDIM + colBase + wc * 64 + n * 16 + fr];
#pragma unroll
  for (int m = 0; m < 4; ++m) {
#pragma unroll
    for (int r = 0; r < 4; ++r) {
      const int sl = tileM * 128 + wr * 64 + m * 16 + kg * 4 + r;
      if (sl < count) {
        const int idx = base + sl;
        const float gate = gate_list[idx];
        const int tok = tok_list[idx];
        float* orow = out + (size_t)tok * DDIM + colBase;
#pragma unroll
        for (int n = 0; n < 4; ++n) {
          const int col = wc * 64 + n * 16 + fr;
          atomicAdd(orow + col, (acc[m][n][r] + bdv[n]) * gate);
        }
      }
    }
  }
}

// ---------------- host launcher ----------------
// Layout A (ws_size >= 151,781,376 B): WdT gets its own region; Wd transpose fused in prep.
//   xb [0,16M) | WuT [16M,48M) | hws [48M,117.96M) | WdT [117.96M,151.5M) | small
// Layout B (fallback = round-11): WdT reuses [0,32M) after up_gemm; separate transpose.
extern "C" void kernel_launch(void* const* d_in, const int* in_sizes, int n_in,
                              void* d_out, int out_size, void* d_ws, size_t ws_size,
                              hipStream_t stream) {
  const float* x     = (const float*)d_in[0];
  const float* noise = (const float*)d_in[1];
  const float* Wg    = (const float*)d_in[2];
  const float* bg    = (const float*)d_in[3];
  const float* Wn    = (const float*)d_in[4];
  const float* bn    = (const float*)d_in[5];
  const float* Wu    = (const float*)d_in[6];
  const float* bu    = (const float*)d_in[7];
  const float* Wd    = (const float*)d_in[8];
  const float* bd    = (const float*)d_in[9];
  float* out = (float*)d_out;
  char* ws = (char*)d_ws;

  const bool bigws = (ws_size >= 151781376ull);

  unsigned short* xb  = (unsigned short*)(ws);                    // 16,777,216 B
  unsigned short* WuT = (unsigned short*)(ws + 16777216);         // 33,554,432 B
  unsigned short* hws = (unsigned short*)(ws + 50331648);         // 67,633,152 B
  unsigned short* WdT = bigws ? (unsigned short*)(ws + 117964800)  // own 32MB region
                              : (unsigned short*)(ws);             // reuse (after up_gemm)
  char* small = bigws ? (ws + 151519232) : (ws + 117964800);
  int*    e0e1      = (int*)(small);                              // 32,768 B
  float2* gg        = (float2*)(small + 32768);                   // 65,536 B
  int*    tok_list  = (int*)(small + 98304);                      // 65,536 B
  float*  gate_list = (float*)(small + 163840);                   // 65,536 B
  int*    counts    = (int*)(small + 229376);
  int*    bases     = (int*)(small + 229408);

  // prep: 4096 cast_x + 4096 trWu + 2048 router + 2048 zero-out [+ 4096 trWd if bigws]
  const int prep_blocks = bigws ? 16384 : 12288;
  prep_kernel<<<prep_blocks, 256, 0, stream>>>(x, noise, Wg, bg, Wn, bn, Wu, Wd,
                                               xb, WuT, WdT, e0e1, gg, (float4*)out);
  compact_kernel<<<NE, 512, 0, stream>>>(e0e1, gg, tok_list, gate_list, counts, bases);
  up_gemm_kernel<<<dim3(16, 64, NE), 256, 0, stream>>>(xb, WuT, bu, tok_list, counts, bases, hws);
  if (!bigws)
    transpose_cast64<<<dim3(DDIM / 64, HDIM / 64, NE), 256, 0, stream>>>(Wd, WdT, HDIM, DDIM);
  down_gemm_kernel<<<dim3(8, 64, NE), 256, 0, stream>>>(hws, WdT, bd, tok_list, gate_list, counts, bases, out);
}